// Round 1
// 279.027 us; speedup vs baseline: 1.0333x; 1.0333x over previous
//
#include <hip/hip_runtime.h>

// Output = conv1x1(x, refine_w, refine_b). Everything else in the reference is
// dead code: `_dead` is unused, and x_back == x exactly (permutation followed
// by its argsort-inverse).
//
// x: (8, 64, 256, 256) fp32, refine_w: (64, 64) [o-major], refine_b: (64,)
// out[b,o,h,w] = sum_c w[o,c] * x[b,c,h,w] + b[o]
//
// Structure (v2): previous version kept float2 acc[64] = 128 VGPRs live ->
// compiler spilled (VGPR_Count=72 < 128 needed), latency-bound at 26% VALU /
// 23% HBM. Now each block's 4 waves split the 64 output channels 4 ways:
// per-thread state = float4 acc[16] = 64 VGPRs (fits). 16B/lane float4
// loads/stores (the 6.29 TB/s pattern). All 4 waves read identical x lines
// (lane = t&63 -> same pixel quad), so L1 absorbs the 4x read amplification.

constexpr int  C   = 64;
constexpr long HW  = 65536;        // 256*256
constexpr long NPIX = 8L * HW;     // 524288 pixels
constexpr int  P   = 4;            // pixels per thread (float4)
constexpr int  OG  = 4;            // o-groups (one per wave pair of the block)
constexpr int  OPT = C / OG;       // 16 output channels per thread
constexpr int  PIX_PER_BLOCK = 64 * P;  // 64 quads * 4 pixels = 256

typedef float f4 __attribute__((ext_vector_type(4)));

__global__ __launch_bounds__(256, 4) void conv1x1_refine_kernel(
    const float* __restrict__ x,
    const float* __restrict__ w,     // (64,64) o-major
    const float* __restrict__ bias,  // (64,)
    float* __restrict__ out)
{
    const int t  = threadIdx.x;
    const int q  = t & 63;                                   // pixel-quad index
    const int og = __builtin_amdgcn_readfirstlane(t >> 6);   // wave-uniform o-group -> SGPR

    const long pix = (long)blockIdx.x * PIX_PER_BLOCK + (long)q * P;
    const long b   = pix >> 16;            // pix / HW (blocks never straddle a batch)
    const long hw  = pix & (HW - 1);       // pix % HW

    const float* xb = x + b * ((long)C * HW) + hw;
    const float* wg = w + og * OPT * C;    // this group's 16 rows of w
    float*       ob = out + b * ((long)C * HW) + (long)og * OPT * HW + hw;

    f4 acc[OPT];
#pragma unroll
    for (int o = 0; o < OPT; ++o) {
        const float bv = bias[og * OPT + o];   // uniform -> s_load
        acc[o] = (f4){bv, bv, bv, bv};
    }

#pragma unroll 4
    for (int c = 0; c < C; ++c) {
        const f4 xv = *reinterpret_cast<const f4*>(xb + (long)c * HW);
#pragma unroll
        for (int o = 0; o < OPT; ++o) {
            const float wv = wg[o * C + c];    // uniform -> s_load, SGPR operand of v_fma
            acc[o].x = fmaf(wv, xv.x, acc[o].x);
            acc[o].y = fmaf(wv, xv.y, acc[o].y);
            acc[o].z = fmaf(wv, xv.z, acc[o].z);
            acc[o].w = fmaf(wv, xv.w, acc[o].w);
        }
    }

    // Streamed output, never re-read: nontemporal to avoid evicting x from LLC
    // (the cross-dispatch L3 residency is already halving FETCH_SIZE).
#pragma unroll
    for (int o = 0; o < OPT; ++o) {
        __builtin_nontemporal_store(acc[o], reinterpret_cast<f4*>(ob + (long)o * HW));
    }
}

extern "C" void kernel_launch(void* const* d_in, const int* in_sizes, int n_in,
                              void* d_out, int out_size, void* d_ws, size_t ws_size,
                              hipStream_t stream)
{
    const float* x  = (const float*)d_in[0];   // x
    const float* rw = (const float*)d_in[11];  // refine_w
    const float* rb = (const float*)d_in[12];  // refine_b
    float* out = (float*)d_out;

    const int threads = 256;
    const int blocks  = (int)(NPIX / PIX_PER_BLOCK);  // 2048
    hipLaunchKernelGGL(conv1x1_refine_kernel, dim3(blocks), dim3(threads), 0, stream,
                       x, rw, rb, out);
}